// Round 1
// baseline (123.279 us; speedup 1.0000x reference)
//
#include <hip/hip_runtime.h>
#include <hip/hip_bf16.h>

typedef __attribute__((ext_vector_type(8))) short short8;
typedef __attribute__((ext_vector_type(4))) float f32x4;

#define CIN   16
#define COUT  64
#define HH    256
#define WW    256
#define OHH   254
#define OWW   254

// LDS patch layout: [18 h][18 w][24 ushort]  (16 ci used + 8 pad for bank spread)
#define WSTRIDE   24
#define ROWSTRIDE (18 * WSTRIDE)   // 432 ushorts per h row

__device__ __forceinline__ ushort f2bf(float f) {
    unsigned u = __builtin_bit_cast(unsigned, f);
    unsigned r = (u + 0x7fffu + ((u >> 16) & 1u)) >> 16;
    return (ushort)r;
}

// Rearrange conv weights (fp32 OIHW [64][16][3][3]) into per-lane bf16 B-fragments:
// wfrag[p][j][lane][r]: k_local = 8*(lane>>4)+r, tap = 2p + (k_local>=16), ci = k_local&15,
// co = 16j + (lane&15). tap==9 (pair 4 upper half) -> 0 so garbage A contributes nothing.
__global__ void prep_weights(const float* __restrict__ wsrc, ushort* __restrict__ wfrag) {
    int idx = blockIdx.x * 256 + threadIdx.x;
    if (idx >= 10240) return;
    int r    = idx & 7;
    int lane = (idx >> 3) & 63;
    int j    = (idx >> 9) & 3;
    int p    = idx >> 11;
    int kl   = ((lane >> 4) << 3) + r;
    int tap  = 2 * p + (kl >> 4);
    int ci   = kl & 15;
    int co   = j * 16 + (lane & 15);
    float v = 0.0f;
    if (tap <= 8) {
        int kh = tap / 3, kw = tap - 3 * (tap / 3);
        v = wsrc[(co * CIN + ci) * 9 + kh * 3 + kw];
    }
    wfrag[idx] = f2bf(v);
}

__global__ __launch_bounds__(256, 2) void conv_min_tanh(
        const float* __restrict__ x, const ushort* __restrict__ wfrag,
        const float* __restrict__ bias, float* __restrict__ out) {
    __shared__ ushort lds[18 * ROWSTRIDE];   // 15552 B

    const int tid = threadIdx.x;
    const int n   = blockIdx.z;
    const int oh0 = blockIdx.y * 16;
    const int ow0 = blockIdx.x * 16;

    // ---- stage input patch (18 x 18 x 16ci) NCHW fp32 -> LDS [h][w][ci] bf16 ----
    const float* xb = x + (size_t)n * CIN * HH * WW;
    for (int it = 0; it < 6; ++it) {
        int idx = tid + it * 256;
        if (idx < 1296) {                       // 18 w * (18 h * 4 cgroups)
            int wp   = idx % 18;
            int rest = idx / 18;
            int cg   = rest & 3;                // ci group of 4
            int hp   = rest >> 2;
            int hg = min(oh0 + hp, HH - 1);     // clamp edges (garbage rows never stored)
            int wg = min(ow0 + wp, WW - 1);
            const float* src = xb + (size_t)(cg * 4) * (HH * WW) + hg * WW + wg;
            ushort u0 = f2bf(src[0]);
            ushort u1 = f2bf(src[HH * WW]);
            ushort u2 = f2bf(src[2 * HH * WW]);
            ushort u3 = f2bf(src[3 * HH * WW]);
            uint2 pk;
            pk.x = (unsigned)u0 | ((unsigned)u1 << 16);
            pk.y = (unsigned)u2 | ((unsigned)u3 << 16);
            *reinterpret_cast<uint2*>(&lds[hp * ROWSTRIDE + wp * WSTRIDE + cg * 4]) = pk;
        }
    }

    const int lane = tid & 63;
    const int wid  = tid >> 6;
    const int g    = lane >> 4;
    const int mm   = lane & 15;

    // ---- B fragments (weights) -> registers, reused across this wave's 4 M-tiles ----
    short8 wf[5][4];
#pragma unroll
    for (int p = 0; p < 5; ++p)
#pragma unroll
        for (int j = 0; j < 4; ++j)
            wf[p][j] = *reinterpret_cast<const short8*>(wfrag + (((p * 4 + j) * 64 + lane) * 8));

    float bj[4];
#pragma unroll
    for (int j = 0; j < 4; ++j) bj[j] = bias[j * 16 + mm];

    // per-pair LDS offset (ushorts), excluding the ohl*ROWSTRIDE term
    int aoff[5];
#pragma unroll
    for (int p = 0; p < 5; ++p) {
        int tap = 2 * p + (g >> 1);
        if (tap > 8) tap = 8;                 // pair-4 upper half: B is zero, read anything valid
        int kh = tap / 3, kw = tap - 3 * (tap / 3);
        aoff[p] = kh * ROWSTRIDE + (mm + kw) * WSTRIDE + (g & 1) * 8;
    }

    __syncthreads();

    // ---- each wave: 4 M-tiles (one oh row of 16 ow each) ----
#pragma unroll
    for (int t = 0; t < 4; ++t) {
        const int ohl = wid * 4 + t;
        f32x4 acc0 = {0.f, 0.f, 0.f, 0.f};
        f32x4 acc1 = {0.f, 0.f, 0.f, 0.f};
        f32x4 acc2 = {0.f, 0.f, 0.f, 0.f};
        f32x4 acc3 = {0.f, 0.f, 0.f, 0.f};
        const int base = ohl * ROWSTRIDE;
#pragma unroll
        for (int p = 0; p < 5; ++p) {
            short8 a = *reinterpret_cast<const short8*>(&lds[base + aoff[p]]);
            acc0 = __builtin_amdgcn_mfma_f32_16x16x32_bf16(a, wf[p][0], acc0, 0, 0, 0);
            acc1 = __builtin_amdgcn_mfma_f32_16x16x32_bf16(a, wf[p][1], acc1, 0, 0, 0);
            acc2 = __builtin_amdgcn_mfma_f32_16x16x32_bf16(a, wf[p][2], acc2, 0, 0, 0);
            acc3 = __builtin_amdgcn_mfma_f32_16x16x32_bf16(a, wf[p][3], acc3, 0, 0, 0);
        }

        // bias + min over the 4 channel tiles (each lane: channels mm, mm+16, mm+32, mm+48)
        float v[4];
#pragma unroll
        for (int r = 0; r < 4; ++r)
            v[r] = fminf(fminf(acc0[r] + bj[0], acc1[r] + bj[1]),
                         fminf(acc2[r] + bj[2], acc3[r] + bj[3]));

        // min across the 16 columns (lanes within each 16-lane group)
#pragma unroll
        for (int mask = 1; mask <= 8; mask <<= 1)
#pragma unroll
            for (int r = 0; r < 4; ++r)
                v[r] = fminf(v[r], __shfl_xor(v[r], mask, 64));

        const int oh = oh0 + ohl;
        if (mm == 0 && oh < OHH) {
#pragma unroll
            for (int r = 0; r < 4; ++r) {
                int ow = ow0 + g * 4 + r;     // D row = 4*(lane>>4) + reg
                if (ow < OWW) {
                    float y = tanhf(tanhf(v[r]));
                    out[((size_t)n * OHH + oh) * OWW + ow] = y;
                }
            }
        }
    }
}

extern "C" void kernel_launch(void* const* d_in, const int* in_sizes, int n_in,
                              void* d_out, int out_size, void* d_ws, size_t ws_size,
                              hipStream_t stream) {
    const float* x = (const float*)d_in[0];
    const float* w = (const float*)d_in[1];
    const float* b = (const float*)d_in[2];
    float* out     = (float*)d_out;
    ushort* wfrag  = (ushort*)d_ws;          // 20 KiB

    prep_weights<<<40, 256, 0, stream>>>(w, wfrag);
    dim3 grid(16, 16, 32);                   // (owT, ohT, n)
    conv_min_tanh<<<grid, dim3(256, 1, 1), 0, stream>>>(x, wfrag, b, out);
}